// Round 1
// baseline (364.799 us; speedup 1.0000x reference)
//
#include <hip/hip_runtime.h>
#include <hip/hip_bf16.h>

#define IN_DIM  64
#define HID     128
#define OUT_DIM 32

typedef short v8s __attribute__((ext_vector_type(8)));
typedef float v4f __attribute__((ext_vector_type(4)));

__device__ __forceinline__ float swishf(float v) {
    // v * sigmoid(v) with native v_exp / v_rcp
    return __fdividef(v, 1.0f + __expf(-v));
}

__device__ __forceinline__ unsigned pk2(float a, float b) {
    __hip_bfloat162 p = __float22bfloat162_rn(make_float2(a, b));
    return *(unsigned*)&p;
}

__device__ __forceinline__ uint2 swish_pack(v4f a) {
    uint2 pk;
    pk.x = pk2(swishf(a[0]), swishf(a[1]));
    pk.y = pk2(swishf(a[2]), swishf(a[3]));
    return pk;
}

// Gather one A-fragment (8 k-consecutive bf16 for this lane) from a row-major
// fp32 weight matrix W[k][c]: lane needs W[k0+j][c0], j=0..7, stride HID floats.
__device__ __forceinline__ v8s load_wfrag(const float* __restrict__ p) {
    union { v8s v; unsigned u[4]; } cv;
    #pragma unroll
    for (int jj = 0; jj < 4; ++jj)
        cv.u[jj] = pk2(p[(2 * jj) * HID], p[(2 * jj + 1) * HID]);
    return cv.v;
}

// Transposed-GEMM structure (C^T = W^T * H^T), weights REGISTER-RESIDENT.
// Block = 4 waves = 4 channel groups (32 ch each); per iter the block does a
// 64-row tile. H handoff between channel-group waves goes through an
// XOR-swizzled unpadded LDS buffer -> conflict-free b128 reads/b64 writes.
__global__ __launch_bounds__(256, 2)
void subnet_mlp(const float* __restrict__ x,  const float* __restrict__ W1,
                const float* __restrict__ b1, const float* __restrict__ Wh,
                const float* __restrict__ bh, const float* __restrict__ Wo,
                const float* __restrict__ bo, float* __restrict__ out,
                int n_iters)
{
    __shared__ __align__(16) short sHa[64][HID];   // 16 KB, swizzled
    __shared__ __align__(16) short sHb[64][HID];   // 16 KB, swizzled
    __shared__ __align__(16) float sPart[4][64];   // per-cg head partials

    const int tid   = threadIdx.x;
    const int o     = blockIdx.x >> 4;    // subnet
    const int slice = blockIdx.x & 15;    // row-slice
    const int lane  = tid & 63;
    const int cg    = tid >> 6;           // wave id = channel group (32 ch)
    const int n     = lane & 15;          // fragment row/col index
    const int q     = lane >> 4;          // quad
    const int cb    = cg * 32;            // channel base of this wave

    // ---- one-time: weight fragments -> registers (80 VGPRs, loop-invariant) ----
    v8s w1f[2][2];                        // [kc][ct]  layer 1, K=64
    #pragma unroll
    for (int kc = 0; kc < 2; ++kc)
        #pragma unroll
        for (int ct = 0; ct < 2; ++ct)
            w1f[kc][ct] = load_wfrag(W1 + (o * IN_DIM + kc * 32 + q * 8) * HID + cb + ct * 16 + n);

    v8s whf[2][4][2];                     // [layer][kc][ct]  hidden, K=128
    #pragma unroll
    for (int l = 0; l < 2; ++l)
        #pragma unroll
        for (int kc = 0; kc < 4; ++kc)
            #pragma unroll
            for (int ct = 0; ct < 2; ++ct)
                whf[l][kc][ct] = load_wfrag(Wh + ((l * OUT_DIM + o) * HID + kc * 32 + q * 8) * HID + cb + ct * 16 + n);

    // biases + head weights, per-lane registers (bias rides the MFMA C-operand)
    v4f b1v[2], bh0v[2], bh1v[2], wov[2];
    #pragma unroll
    for (int ct = 0; ct < 2; ++ct) {
        const int c4 = cb + ct * 16 + 4 * q;
        b1v[ct]  = *(const v4f*)(b1 + o * HID + c4);
        bh0v[ct] = *(const v4f*)(bh + o * HID + c4);
        bh1v[ct] = *(const v4f*)(bh + (OUT_DIM + o) * HID + c4);
        wov[ct]  = *(const v4f*)(Wo + o * HID + c4);
    }
    const float bo_v = bo[o];

    // ---- loop-invariant swizzled LDS byte offsets (zero VALU in main loop) ----
    // element (row r, ch c) lives at byte r*256 + ((2c) ^ ((r&7)<<4)); r&7 == n&7
    const int swz = (n & 7) << 4;
    int rd[4], wr[2];
    #pragma unroll
    for (int kc = 0; kc < 4; ++kc) rd[kc] = n * 256 + ((kc * 64 + q * 16) ^ swz);
    #pragma unroll
    for (int ct = 0; ct < 2; ++ct) wr[ct] = n * 256 + ((cb * 2 + ct * 32 + q * 8) ^ swz);

    char* const hA = (char*)sHa;
    char* const hB = (char*)sHb;

    for (int it = 0; it < n_iters; ++it) {
        const int n0 = (slice * n_iters + it) * 64;

        // ---- x fragments (B-operand, row-major, k-contiguous) ----
        v8s xc[4][2];
        #pragma unroll
        for (int rt = 0; rt < 4; ++rt) {
            const float* xp = x + (n0 + rt * 16 + n) * IN_DIM + q * 8;
            #pragma unroll
            for (int kc = 0; kc < 2; ++kc) {
                float4 f0 = *(const float4*)(xp + kc * 32);
                float4 f1 = *(const float4*)(xp + kc * 32 + 4);
                union { v8s v; unsigned u[4]; } cv;
                cv.u[0] = pk2(f0.x, f0.y); cv.u[1] = pk2(f0.z, f0.w);
                cv.u[2] = pk2(f1.x, f1.y); cv.u[3] = pk2(f1.z, f1.w);
                xc[rt][kc] = cv.v;
            }
        }

        // ================= layer 1: C^T = W1^T @ X^T =================
        #pragma unroll
        for (int rt = 0; rt < 4; ++rt) {
            v4f a0 = b1v[0], a1 = b1v[1];
            #pragma unroll
            for (int kc = 0; kc < 2; ++kc) {
                a0 = __builtin_amdgcn_mfma_f32_16x16x32_bf16(w1f[kc][0], xc[rt][kc], a0, 0, 0, 0);
                a1 = __builtin_amdgcn_mfma_f32_16x16x32_bf16(w1f[kc][1], xc[rt][kc], a1, 0, 0, 0);
            }
            *(uint2*)(hA + rt * 4096 + wr[0]) = swish_pack(a0);
            *(uint2*)(hA + rt * 4096 + wr[1]) = swish_pack(a1);
        }
        __syncthreads();

        // ================= layer 2 =================
        #pragma unroll
        for (int rt = 0; rt < 4; ++rt) {
            v4f a0 = bh0v[0], a1 = bh0v[1];
            #pragma unroll
            for (int kc = 0; kc < 4; ++kc) {
                v8s hb = *(const v8s*)(hA + rt * 4096 + rd[kc]);
                a0 = __builtin_amdgcn_mfma_f32_16x16x32_bf16(whf[0][kc][0], hb, a0, 0, 0, 0);
                a1 = __builtin_amdgcn_mfma_f32_16x16x32_bf16(whf[0][kc][1], hb, a1, 0, 0, 0);
            }
            *(uint2*)(hB + rt * 4096 + wr[0]) = swish_pack(a0);
            *(uint2*)(hB + rt * 4096 + wr[1]) = swish_pack(a1);
        }
        __syncthreads();

        // ================= layer 3 + fused head =================
        #pragma unroll
        for (int rt = 0; rt < 4; ++rt) {
            v4f a0 = bh1v[0], a1 = bh1v[1];
            #pragma unroll
            for (int kc = 0; kc < 4; ++kc) {
                v8s hb = *(const v8s*)(hB + rt * 4096 + rd[kc]);
                a0 = __builtin_amdgcn_mfma_f32_16x16x32_bf16(whf[1][kc][0], hb, a0, 0, 0, 0);
                a1 = __builtin_amdgcn_mfma_f32_16x16x32_bf16(whf[1][kc][1], hb, a1, 0, 0, 0);
            }
            float p = swishf(a0[0]) * wov[0][0] + swishf(a0[1]) * wov[0][1]
                    + swishf(a0[2]) * wov[0][2] + swishf(a0[3]) * wov[0][3]
                    + swishf(a1[0]) * wov[1][0] + swishf(a1[1]) * wov[1][1]
                    + swishf(a1[2]) * wov[1][2] + swishf(a1[3]) * wov[1][3];
            p += __shfl_xor(p, 16);              // reduce over quads (q)
            p += __shfl_xor(p, 32);
            if (q == 0) sPart[cg][rt * 16 + n] = p;
        }
        __syncthreads();

        // cross-channel-group reduce + store (one wave)
        if (tid < 64) {
            const int row = n0 + tid;
            out[row * OUT_DIM + o] =
                sPart[0][tid] + sPart[1][tid] + sPart[2][tid] + sPart[3][tid] + bo_v;
        }
        // next iter's sHa writes are fenced by the two barriers inside this iter;
        // sPart reuse is fenced by barriers 1+2 of the next iter.
    }
}

extern "C" void kernel_launch(void* const* d_in, const int* in_sizes, int n_in,
                              void* d_out, int out_size, void* d_ws, size_t ws_size,
                              hipStream_t stream) {
    const float* x  = (const float*)d_in[0];
    const float* W1 = (const float*)d_in[1];
    const float* b1 = (const float*)d_in[2];
    const float* Wh = (const float*)d_in[3];
    const float* bh = (const float*)d_in[4];
    const float* Wo = (const float*)d_in[5];
    const float* bo = (const float*)d_in[6];
    float* out = (float*)d_out;

    const int N       = in_sizes[0] / IN_DIM;  // 32768
    const int n_tiles = N / 64;                // 512 tiles of 64 rows
    const int n_iters = n_tiles / 16;          // 32 tiles per block

    dim3 grid(OUT_DIM * 16);                   // 512 blocks: 32 subnets x 16 slices
    dim3 block(256);                           // 4 waves; 2 blocks co-resident/CU
    subnet_mlp<<<grid, block, 0, stream>>>(x, W1, b1, Wh, bh, Wo, bo, out, n_iters);
}